// Round 4
// baseline (1090.893 us; speedup 1.0000x reference)
//
#include <hip/hip_runtime.h>
#include <hip/hip_bf16.h>
#include <cstdint>
#include <cstddef>

#define BB 16
#define NN 128
#define MM 1024
#define DN 512
#define DE 256
#define WN 128
#define WE 128
#define PP 512
#define HIDW 256
#define CIW 512

#define NBLK 384   // grid size; co-resident: 256 CU x 2 blocks/CU = 512 >= 384

typedef __attribute__((ext_vector_type(8))) short s16x8;
typedef __attribute__((ext_vector_type(4))) float f32x4;

__device__ __forceinline__ float bf2f(unsigned short u) {
    unsigned int x = ((unsigned int)u) << 16;
    union { unsigned int i; float f; } c; c.i = x; return c.f;
}
__device__ __forceinline__ short f2b(float f) {
    __hip_bfloat16 h = __float2bfloat16(f);
    return *reinterpret_cast<short*>(&h);
}
__device__ __forceinline__ void gl_lds16(const ushort* g, ushort* l) {
    __builtin_amdgcn_global_load_lds(
        (const __attribute__((address_space(1))) unsigned int*)g,
        (__attribute__((address_space(3))) unsigned int*)l,
        16, 0, 0);
}

// Manual grid barrier: monotonic arrival counter (no reset -> no clobber race
// between back-to-back barriers). AGENT-scope atomics + __threadfence give
// cross-XCD release/acquire (L2 wb/inv on gfx950). Bounded spin as a
// deadlock escape (co-residency is guaranteed by launch_bounds + grid<=512).
__device__ __forceinline__ void grid_barrier(unsigned* cnt, unsigned phase) {
    __syncthreads();
    if (threadIdx.x == 0) {
        __threadfence();   // release: my phase's writes visible device-wide
        __hip_atomic_fetch_add(cnt, 1u, __ATOMIC_ACQ_REL, __HIP_MEMORY_SCOPE_AGENT);
        unsigned target = (unsigned)NBLK * (phase + 1u);
        long spin = 0;
        while (__hip_atomic_load(cnt, __ATOMIC_ACQUIRE, __HIP_MEMORY_SCOPE_AGENT) < target) {
            __builtin_amdgcn_s_sleep(8);
            if (++spin > (1L << 20)) break;   // escape hatch: fail loud, not hang
        }
        __threadfence();   // acquire: drop stale L1/L2 before reading others' data
    }
    __syncthreads();
}

struct MegaP {
    const float *nf, *ef, *adj, *la;
    const int *eidx, *opair, *nobj, *nedg;
    const float *Wn, *We, *Wn2, *We2;
    const float *scrW1, *scrb1, *scrW2, *scrb2;
    const float *lrW1, *lrb1, *lrW2, *lrb2;
    const float *mrW1, *mrb1, *mrW2, *mrb2;
    float *Y, *Xp, *node_emb, *G1;
    __hip_bfloat16 *ci, *hid, *W1t, *WncT, *WeT, *We2T;
    float *b1cat;
    unsigned *gbar;
    float *outp;
};

union Smem {
    struct { ushort As[128 * 32]; ushort Bs[128 * 32];
             unsigned rowoff[128]; float rowval[128]; } g;   // fproj / k6 (17 KB)
    struct { float As[16 * 129]; } k2;                        // 8.3 KB
    struct { int idxs[2][MM]; float vals[2][MM]; int cnt[2]; } k4; // 16.4 KB
    struct { int pi0[16], pi1[16]; float nm0[16], nm1[16]; } k5;
    struct { float w2s[32 * 257]; } k7;                       // 32.9 KB
};

__global__ __launch_bounds__(256, 2) void mega(MegaP P) {
    __shared__ Smem S;
    const int t   = threadIdx.x;
    const int bid = blockIdx.x;
    const int nb  = gridDim.x;

    // ================= P0: weight prep (was k0) =================
    for (int vb = bid; vb < 1281; vb += nb) {
        if (vb < 768) {
            int h = vb >> 8, n = vb & 255;
            const float* W = (h == 0) ? P.lrW1 : (h == 1) ? P.scrW1 : P.mrW1;
            P.W1t[(size_t)vb * 512 + t]       = __float2bfloat16(W[t * 256 + n]);
            P.W1t[(size_t)vb * 512 + t + 256] = __float2bfloat16(W[(t + 256) * 256 + n]);
        } else if (vb == 768) {
            P.b1cat[t]       = P.lrb1[t];
            P.b1cat[256 + t] = P.scrb1[t];
            P.b1cat[512 + t] = P.mrb1[t];
        } else if (vb < 897) {
            int n = vb - 769;
            P.WeT[(size_t)n * 256 + t] = __float2bfloat16(P.We[t * 128 + n]);
        } else if (vb < 1153) {
            int n = vb - 897;
            const float* W = (n < 128) ? P.Wn : P.Wn2;
            int c = n & 127;
            P.WncT[(size_t)n * 512 + t]       = __float2bfloat16(W[t * 128 + c]);
            P.WncT[(size_t)n * 512 + t + 256] = __float2bfloat16(W[(t + 256) * 128 + c]);
        } else {
            int n = vb - 1153;
            P.We2T[(size_t)n * 256 + t] = __float2bfloat16(P.We2[t * 128 + n]);
        }
    }
    grid_barrier(P.gbar, 0);

    // ================= P1: fused projection GEMMs (was fproj) =================
    {
        const int lane = t & 63, w = t >> 6;
        const int wr = w >> 1, wc = w & 1;
        const int arow = w * 32 + (lane >> 2);
        const int ak = (lane & 3) * 8;
        const int qk = (lane >> 4) * 8;
        const int fr = lane & 15;
        const int sr = t >> 2;
        const int sk = (t & 3) * 8;
        for (int vb = bid; vb < 224; vb += nb) {
            int route, mb, nbk, K;
            const ushort* Bt;
            if (vb < 32)       { route = 0; mb = vb >> 1;  nbk = vb & 1; K = 512; Bt = (const ushort*)P.WncT; }
            else if (vb < 160) { route = 1; mb = vb - 32;  nbk = 0;      K = 256; Bt = (const ushort*)P.WeT;  }
            else               { route = 2; mb = vb - 160; nbk = 0;      K = 256; Bt = (const ushort*)P.We2T; }
            int row0 = mb * 128, col0 = nbk * 128;
            __syncthreads();   // LDS WAR guard across virtual blocks
            if (t < 128) {
                int r = row0 + t;
                unsigned off; float valid = 1.f;
                if (route == 0) {
                    int b = r >> 7, i = r & 127;
                    off = (unsigned)r * DN;
                    valid = (i < P.nobj[b]) ? 1.f : 0.f;
                } else if (route == 1) {
                    int b = r >> 10, m = r & 1023;
                    int src = P.eidx[b * 2 * MM + m];
                    int dst = P.eidx[b * 2 * MM + MM + m];
                    off = (unsigned)((b * NN + src) * NN + dst) * DE;
                    valid = (m < P.nedg[b]) ? 1.f : 0.f;
                } else {
                    int b = r >> 9, p = r & 511;
                    int i0 = P.opair[(b * PP + p) * 2];
                    int i1 = P.opair[(b * PP + p) * 2 + 1];
                    off = (unsigned)((b * NN + i0) * NN + i1) * DE;
                }
                S.g.rowoff[t] = off; S.g.rowval[t] = valid;
            }
            const float* Asrc = (route == 0) ? P.nf : P.ef;
            f32x4 acc[4][4];
            #pragma unroll
            for (int i = 0; i < 4; ++i)
                #pragma unroll
                for (int j = 0; j < 4; ++j) acc[i][j] = (f32x4){0.f, 0.f, 0.f, 0.f};

            for (int k0 = 0; k0 < K; k0 += 32) {
                __syncthreads();
                gl_lds16(&Bt[(size_t)(col0 + sr) * K + k0 + sk],      &S.g.Bs[t * 8]);
                gl_lds16(&Bt[(size_t)(col0 + sr + 64) * K + k0 + sk], &S.g.Bs[t * 8 + 2048]);
                {
                    unsigned o0 = S.g.rowoff[arow] + k0 + ak;
                    unsigned o1 = S.g.rowoff[arow + 16] + k0 + ak;
                    float m0 = S.g.rowval[arow], m1 = S.g.rowval[arow + 16];
                    float4 a0 = *(const float4*)&Asrc[o0];
                    float4 a1 = *(const float4*)&Asrc[o0 + 4];
                    float4 b0 = *(const float4*)&Asrc[o1];
                    float4 b1 = *(const float4*)&Asrc[o1 + 4];
                    s16x8 pa, pb;
                    pa[0]=f2b(a0.x*m0); pa[1]=f2b(a0.y*m0); pa[2]=f2b(a0.z*m0); pa[3]=f2b(a0.w*m0);
                    pa[4]=f2b(a1.x*m0); pa[5]=f2b(a1.y*m0); pa[6]=f2b(a1.z*m0); pa[7]=f2b(a1.w*m0);
                    pb[0]=f2b(b0.x*m1); pb[1]=f2b(b0.y*m1); pb[2]=f2b(b0.z*m1); pb[3]=f2b(b0.w*m1);
                    pb[4]=f2b(b1.x*m1); pb[5]=f2b(b1.y*m1); pb[6]=f2b(b1.z*m1); pb[7]=f2b(b1.w*m1);
                    *(s16x8*)&S.g.As[arow * 32 + ak]        = pa;
                    *(s16x8*)&S.g.As[(arow + 16) * 32 + ak] = pb;
                }
                __syncthreads();
                s16x8 af[4], bfv[4];
                #pragma unroll
                for (int mi = 0; mi < 4; ++mi)
                    af[mi] = *(const s16x8*)&S.g.As[(wr * 64 + mi * 16 + fr) * 32 + qk];
                #pragma unroll
                for (int ni = 0; ni < 4; ++ni)
                    bfv[ni] = *(const s16x8*)&S.g.Bs[(wc * 64 + ni * 16 + fr) * 32 + qk];
                #pragma unroll
                for (int mi = 0; mi < 4; ++mi)
                    #pragma unroll
                    for (int ni = 0; ni < 4; ++ni)
                        acc[mi][ni] = __builtin_amdgcn_mfma_f32_16x16x32_bf16(
                            af[mi], bfv[ni], acc[mi][ni], 0, 0, 0);
            }
            int crow = (lane >> 4) * 4;
            #pragma unroll
            for (int mi = 0; mi < 4; ++mi) {
                #pragma unroll
                for (int ni = 0; ni < 4; ++ni) {
                    int gc = col0 + wc * 64 + ni * 16 + fr;
                    int gr = row0 + wr * 64 + mi * 16 + crow;
                    #pragma unroll
                    for (int rg = 0; rg < 4; ++rg) {
                        float v = acc[mi][ni][rg];
                        int r = gr + rg;
                        if (route == 0) {
                            if (gc < 128) P.Y [(size_t)r * WN + gc]       = v;
                            else          P.Xp[(size_t)r * WN + gc - 128] = v;
                        } else if (route == 1) {
                            P.G1[(size_t)r * WE + gc] = v;
                        } else {
                            P.ci[(size_t)r * CIW + 384 + gc] = __float2bfloat16(fmaxf(v, 0.f));
                        }
                    }
                }
            }
        }
    }
    grid_barrier(P.gbar, 1);

    // ================= P2: node GCN (was k2) =================
    for (int vb = bid; vb < 256; vb += nb) {
        int b  = vb >> 4;
        int i0 = ((vb >> 1) & 7) * 16;
        int ch = vb & 1;
        int s  = P.nobj[b];
        __syncthreads();   // LDS WAR guard
        if (t < 128) {
            for (int rr = 0; rr < 16; ++rr) {
                int i = i0 + rr;
                float v = 0.f;
                if (i < s) {
                    v = P.adj[(size_t)(b * NN + i) * NN + t] * ((t < s) ? 1.f : 0.f);
                    if (t == i) v += 1.f;
                }
                S.k2.As[rr * 129 + t] = v;
            }
        }
        __syncthreads();
        int c  = ch * 64 + (t & 63);
        int rb = (t >> 6) * 4;
        float acc[4] = {0.f, 0.f, 0.f, 0.f};
        for (int j = 0; j < NN; ++j) {
            float yv = P.Y[(b * NN + j) * WN + c];
            #pragma unroll
            for (int r = 0; r < 4; ++r) acc[r] += S.k2.As[(rb + r) * 129 + j] * yv;
        }
        #pragma unroll
        for (int r = 0; r < 4; ++r) {
            int i = i0 + rb + r;
            P.node_emb[(b * NN + i) * 256 + c]       = fmaxf(acc[r], 0.f);
            P.node_emb[(b * NN + i) * 256 + 128 + c] = 0.f;
        }
    }
    grid_barrier(P.gbar, 2);

    // ================= P3: line GCN + scatter (was k4), 2 edges/block =================
    {
        const int half = t >> 7;
        const int ch   = t & 127;
        for (int vb = bid; vb < 8192; vb += nb) {
            int b = vb >> 9;
            int m = (vb & 511) * 2 + half;
            int se = P.nedg[b];
            bool act = (m < se);
            __syncthreads();              // prev vb's reads done
            if (ch == 0) S.k4.cnt[half] = 0;
            __syncthreads();
            if (act) {
                const float4* larow = (const float4*)(P.la + ((size_t)b * MM + m) * MM);
                #pragma unroll
                for (int pass = 0; pass < 2; ++pass) {
                    int j4 = pass * 128 + ch;
                    float4 v = larow[j4];
                    int j0 = j4 * 4;
                    if (v.x != 0.f) { int p = atomicAdd(&S.k4.cnt[half], 1); S.k4.idxs[half][p] = j0;     S.k4.vals[half][p] = v.x; }
                    if (v.y != 0.f) { int p = atomicAdd(&S.k4.cnt[half], 1); S.k4.idxs[half][p] = j0 + 1; S.k4.vals[half][p] = v.y; }
                    if (v.z != 0.f) { int p = atomicAdd(&S.k4.cnt[half], 1); S.k4.idxs[half][p] = j0 + 2; S.k4.vals[half][p] = v.z; }
                    if (v.w != 0.f) { int p = atomicAdd(&S.k4.cnt[half], 1); S.k4.idxs[half][p] = j0 + 3; S.k4.vals[half][p] = v.w; }
                }
            }
            __syncthreads();
            if (act) {
                int n = S.k4.cnt[half];
                const float* g1b = P.G1 + (size_t)b * MM * WE;
                float acc = g1b[m * WE + ch];
                for (int p = 0; p < n; ++p)
                    acc += S.k4.vals[half][p] * g1b[S.k4.idxs[half][p] * WE + ch];
                float gv = fmaxf(acc, 0.f);
                int src = P.eidx[b * 2 * MM + m];
                atomicAdd(&P.node_emb[((size_t)b * NN + src) * 256 + 128 + ch], gv);
            }
        }
    }
    grid_barrier(P.gbar, 3);

    // ================= P4: build ci[:,0:384] (was k5a) =================
    for (int vb = bid; vb < 512; vb += nb) {
        int b     = vb >> 5;
        int pbase = (vb & 31) * 16;
        int s     = P.nobj[b];
        __syncthreads();   // LDS WAR guard
        if (t < 16) {
            int p  = pbase + t;
            int i0 = P.opair[(b * PP + p) * 2];
            int i1 = P.opair[(b * PP + p) * 2 + 1];
            S.k5.pi0[t] = i0; S.k5.pi1[t] = i1;
            S.k5.nm0[t] = (i0 < s) ? 1.f : 0.f;
            S.k5.nm1[t] = (i1 < s) ? 1.f : 0.f;
        }
        __syncthreads();
        for (int pp = 0; pp < 16; ++pp) {
            int i0 = S.k5.pi0[pp], i1 = S.k5.pi1[pp];
            int p  = pbase + pp;
            __hip_bfloat16* cirow = P.ci + (size_t)(b * PP + p) * CIW;
            float m0f = (t < 128) ? 1.f : S.k5.nm0[pp];
            float m1f = (t < 128) ? 1.f : S.k5.nm1[pp];
            float v = P.node_emb[(b * NN + i0) * 256 + t] * m0f
                    + P.node_emb[(b * NN + i1) * 256 + t] * m1f;
            cirow[t] = __float2bfloat16(v);
            if (t < 128) {
                float pm = P.Xp[(b * NN + i0) * WN + t] + P.Xp[(b * NN + i1) * WN + t];
                cirow[256 + t] = __float2bfloat16(fmaxf(pm, 0.f));
            }
        }
    }
    grid_barrier(P.gbar, 4);

    // ================= P5: MLP layer 1 MFMA (was k6) =================
    {
        const int lane = t & 63, w = t >> 6;
        const int wr = w >> 1, wc = w & 1;
        const int qk = (lane >> 4) * 8;
        const int fr = lane & 15;
        const int sr = t >> 2;
        const int sk = (t & 3) * 8;
        const ushort* A  = (const ushort*)P.ci;
        const ushort* Bt = (const ushort*)P.W1t;
        for (int vb = bid; vb < 384; vb += nb) {
            int col0 = (vb % 6) * 128;
            int row0 = (vb / 6) * 128;
            f32x4 acc[4][4];
            #pragma unroll
            for (int i = 0; i < 4; ++i)
                #pragma unroll
                for (int j = 0; j < 4; ++j) acc[i][j] = (f32x4){0.f, 0.f, 0.f, 0.f};
            for (int k0 = 0; k0 < CIW; k0 += 32) {
                __syncthreads();
                gl_lds16(&A [(size_t)(row0 + sr) * CIW + k0 + sk],      &S.g.As[t * 8]);
                gl_lds16(&A [(size_t)(row0 + sr + 64) * CIW + k0 + sk], &S.g.As[t * 8 + 2048]);
                gl_lds16(&Bt[(size_t)(col0 + sr) * CIW + k0 + sk],      &S.g.Bs[t * 8]);
                gl_lds16(&Bt[(size_t)(col0 + sr + 64) * CIW + k0 + sk], &S.g.Bs[t * 8 + 2048]);
                __syncthreads();
                s16x8 af[4], bfv[4];
                #pragma unroll
                for (int mi = 0; mi < 4; ++mi)
                    af[mi] = *(const s16x8*)&S.g.As[(wr * 64 + mi * 16 + fr) * 32 + qk];
                #pragma unroll
                for (int ni = 0; ni < 4; ++ni)
                    bfv[ni] = *(const s16x8*)&S.g.Bs[(wc * 64 + ni * 16 + fr) * 32 + qk];
                #pragma unroll
                for (int mi = 0; mi < 4; ++mi)
                    #pragma unroll
                    for (int ni = 0; ni < 4; ++ni)
                        acc[mi][ni] = __builtin_amdgcn_mfma_f32_16x16x32_bf16(
                            af[mi], bfv[ni], acc[mi][ni], 0, 0, 0);
            }
            int crow = (lane >> 4) * 4;
            #pragma unroll
            for (int mi = 0; mi < 4; ++mi) {
                #pragma unroll
                for (int ni = 0; ni < 4; ++ni) {
                    int gc = col0 + wc * 64 + ni * 16 + fr;
                    int gr = row0 + wr * 64 + mi * 16 + crow;
                    float bias = P.b1cat[gc];
                    #pragma unroll
                    for (int rg = 0; rg < 4; ++rg) {
                        float v = fmaxf(acc[mi][ni][rg] + bias, 0.f);
                        P.hid[(size_t)(gr + rg) * 768 + gc] = __float2bfloat16(v);
                    }
                }
            }
        }
    }
    grid_barrier(P.gbar, 5);

    // ================= P6: MLP layer 2 (was k7), weights staged once =================
    {
        for (int o = 0; o < 32; ++o) {
            float v;
            if (o < 9)       v = P.lrW2[t * 9 + o];
            else if (o < 15) v = P.scrW2[t * 6 + (o - 9)];
            else             v = P.mrW2[t * 17 + (o - 15)];
            S.k7.w2s[o * 257 + t] = v;
        }
        __syncthreads();
        int o = t & 31;
        int seg = (o < 9) ? 0 : ((o < 15) ? 1 : 2);
        const float* wr = &S.k7.w2s[o * 257];
        float bias = (o < 9) ? P.lrb2[o] : ((o < 15) ? P.scrb2[o - 9] : P.mrb2[o - 15]);
        for (int vb = bid; vb < 1024; vb += nb) {
            int p = vb * 8 + (t >> 5);
            const ushort* hr = (const ushort*)P.hid + (size_t)p * 768 + seg * 256;
            float acc = bias;
            for (int k = 0; k < HIDW; k += 8) {
                s16x8 u = *(const s16x8*)&hr[k];
                acc += bf2f((unsigned short)u[0]) * wr[k]
                     + bf2f((unsigned short)u[1]) * wr[k + 1]
                     + bf2f((unsigned short)u[2]) * wr[k + 2]
                     + bf2f((unsigned short)u[3]) * wr[k + 3]
                     + bf2f((unsigned short)u[4]) * wr[k + 4]
                     + bf2f((unsigned short)u[5]) * wr[k + 5]
                     + bf2f((unsigned short)u[6]) * wr[k + 6]
                     + bf2f((unsigned short)u[7]) * wr[k + 7];
            }
            if (o < 9)       P.outp[(size_t)p * 9 + o] = acc;
            else if (o < 15) P.outp[8192 * 9 + (size_t)p * 6 + (o - 9)] = acc;
            else             P.outp[8192 * 15 + (size_t)p * 17 + (o - 15)] = acc;
        }
    }
}

// ----------------------------------------------------------------
extern "C" void kernel_launch(void* const* d_in, const int* in_sizes, int n_in,
                              void* d_out, int out_size, void* d_ws, size_t ws_size,
                              hipStream_t stream) {
    float* ws = (float*)d_ws;
    float* Y        = ws;
    float* Xp       = Y + 262144;
    float* node_emb = Xp + 262144;
    float* G1       = node_emb + 524288;
    float* base     = G1 + 2097152;
    __hip_bfloat16* ci   = (__hip_bfloat16*)base;
    __hip_bfloat16* hid  = (__hip_bfloat16*)(base + 2097152);
    __hip_bfloat16* W1t  = (__hip_bfloat16*)(base + 2097152 + 3145728);
    __hip_bfloat16* WncT = (__hip_bfloat16*)(base + 2097152 + 3145728 + 196608);
    __hip_bfloat16* WeT  = (__hip_bfloat16*)(base + 2097152 + 3145728 + 196608 + 65536);
    __hip_bfloat16* We2T = (__hip_bfloat16*)(base + 2097152 + 3145728 + 196608 + 65536 + 16384);
    float* b1cat = base + 2097152 + 3145728 + 196608 + 65536 + 16384 + 16384;
    unsigned* gbar = (unsigned*)(b1cat + 1024);   // barrier counter (64B zeroed)

    MegaP hp;
    hp.nf    = (const float*)d_in[0];
    hp.ef    = (const float*)d_in[1];
    hp.adj   = (const float*)d_in[2];
    hp.la    = (const float*)d_in[3];
    hp.eidx  = (const int*)d_in[4];
    hp.opair = (const int*)d_in[5];
    hp.nobj  = (const int*)d_in[6];
    hp.nedg  = (const int*)d_in[7];
    hp.Wn    = (const float*)d_in[8];
    hp.We    = (const float*)d_in[9];
    hp.Wn2   = (const float*)d_in[10];
    hp.We2   = (const float*)d_in[11];
    hp.scrW1 = (const float*)d_in[12];
    hp.scrb1 = (const float*)d_in[13];
    hp.scrW2 = (const float*)d_in[14];
    hp.scrb2 = (const float*)d_in[15];
    hp.lrW1  = (const float*)d_in[16];
    hp.lrb1  = (const float*)d_in[17];
    hp.lrW2  = (const float*)d_in[18];
    hp.lrb2  = (const float*)d_in[19];
    hp.mrW1  = (const float*)d_in[20];
    hp.mrb1  = (const float*)d_in[21];
    hp.mrW2  = (const float*)d_in[22];
    hp.mrb2  = (const float*)d_in[23];
    hp.Y = Y; hp.Xp = Xp; hp.node_emb = node_emb; hp.G1 = G1;
    hp.ci = ci; hp.hid = hid; hp.W1t = W1t; hp.WncT = WncT;
    hp.WeT = WeT; hp.We2T = We2T; hp.b1cat = b1cat;
    hp.gbar = gbar;
    hp.outp = (float*)d_out;

    hipMemsetAsync(gbar, 0, 64, stream);
    mega<<<dim3(NBLK), dim3(256), 0, stream>>>(hp);
}

// Round 5
// 459.402 us; speedup vs baseline: 2.3746x; 2.3746x over previous
//
#include <hip/hip_runtime.h>
#include <hip/hip_bf16.h>
#include <cstdint>
#include <cstddef>

#define BB 16
#define NN 128
#define MM 1024
#define DN 512
#define DE 256
#define WN 128
#define WE 128
#define PP 512
#define HIDW 256
#define CIW 512

typedef __attribute__((ext_vector_type(8))) short s16x8;
typedef __attribute__((ext_vector_type(4))) float f32x4;

__device__ __forceinline__ float bf2f(unsigned short u) {
    unsigned int x = ((unsigned int)u) << 16;
    union { unsigned int i; float f; } c; c.i = x; return c.f;
}
__device__ __forceinline__ short f2b(float f) {
    __hip_bfloat16 h = __float2bfloat16(f);
    return *reinterpret_cast<short*>(&h);
}
__device__ __forceinline__ void gl_lds16(const ushort* g, ushort* l) {
    __builtin_amdgcn_global_load_lds(
        (const __attribute__((address_space(1))) unsigned int*)g,
        (__attribute__((address_space(3))) unsigned int*)l,
        16, 0, 0);
}

// Bs octet swizzle: octet position q in {0,8,16,24} XORed by row low bits.
// Bijective per row; spreads B-side LDS banks 4x on both write and read.
#define BSWZ(row, q) ((q) ^ (((row) & 3) << 3))

// ---------------------------------------------------------------- FPROJ:
// blocks 0..223: 3-route MFMA GEMM (gather fused into A-staging), B staged
//   DIRECTLY from original [K][128] f32 weights (coalesced along N).
//  route0 (blk   0..31 ): [Xmask]@[Wn|Wn2]  M=2048 N=256 K=512 -> Y,Xp f32
//  route1 (blk  32..159): [Eg*emask]@We     M=16384 N=128 K=256 -> G1 f32
//  route2 (blk 160..223): relu(ef_pair@We2) M=8192 N=128 K=256 -> ci[:,384:]
// blocks 224..255: zero AGG (so k2-part of k24 need not, avoiding a race).
__global__ __launch_bounds__(256) void fproj(
    const float* __restrict__ nf, const float* __restrict__ ef,
    const int* __restrict__ eidx, const int* __restrict__ opair,
    const int* __restrict__ nobj, const int* __restrict__ nedg,
    const float* __restrict__ Wn, const float* __restrict__ Wn2,
    const float* __restrict__ We, const float* __restrict__ We2,
    float* __restrict__ Y, float* __restrict__ Xp,
    float* __restrict__ G1, __hip_bfloat16* __restrict__ ci,
    float* __restrict__ AGG)
{
    int blk = blockIdx.x;
    int t   = threadIdx.x;

    if (blk >= 224) {                      // ---- zero AGG (1 MB) ----
        float4* a4 = (float4*)AGG;
        int base = (blk - 224) * 256 + t;  // 8192 threads, 65536 float4
        #pragma unroll
        for (int i = 0; i < 8; ++i) a4[base + i * 8192] = (float4){0.f,0.f,0.f,0.f};
        return;
    }

    __shared__ ushort As[128 * 32];
    __shared__ ushort Bs[128 * 32];
    __shared__ unsigned rowoff[128];
    __shared__ float    rowval[128];

    int route, mb, nbk, K;
    const float* Wsrc;
    if (blk < 32)       { route = 0; mb = blk >> 1;  nbk = blk & 1; K = 512; Wsrc = nbk ? Wn2 : Wn; }
    else if (blk < 160) { route = 1; mb = blk - 32;  nbk = 0;       K = 256; Wsrc = We;  }
    else                { route = 2; mb = blk - 160; nbk = 0;       K = 256; Wsrc = We2; }
    int row0 = mb * 128, col0 = nbk * 128;

    if (t < 128) {
        int r = row0 + t;
        unsigned off; float valid = 1.f;
        if (route == 0) {
            int b = r >> 7, i = r & 127;
            off = (unsigned)r * DN;
            valid = (i < nobj[b]) ? 1.f : 0.f;
        } else if (route == 1) {
            int b = r >> 10, m = r & 1023;
            int src = eidx[b * 2 * MM + m];
            int dst = eidx[b * 2 * MM + MM + m];
            off = (unsigned)((b * NN + src) * NN + dst) * DE;
            valid = (m < nedg[b]) ? 1.f : 0.f;
        } else {
            int b = r >> 9, p = r & 511;
            int i0 = opair[(b * PP + p) * 2];
            int i1 = opair[(b * PP + p) * 2 + 1];
            off = (unsigned)((b * NN + i0) * NN + i1) * DE;
        }
        rowoff[t] = off; rowval[t] = valid;
    }

    const float* Asrc = (route == 0) ? nf : ef;
    int lane = t & 63;
    int w    = t >> 6;
    int wr   = w >> 1, wc = w & 1;
    int arow = w * 32 + (lane >> 2);
    int ak   = (lane & 3) * 8;
    int qk   = (lane >> 4) * 8;
    int fr   = lane & 15;
    int nid  = t & 127;          // B-staging: output row (N within tile)
    int koct = t >> 7;           // B-staging: k-octet selector
    f32x4 acc[4][4];
    #pragma unroll
    for (int i = 0; i < 4; ++i)
        #pragma unroll
        for (int j = 0; j < 4; ++j) acc[i][j] = (f32x4){0.f, 0.f, 0.f, 0.f};

    for (int k0 = 0; k0 < K; k0 += 32) {
        __syncthreads();
        // B tile: direct from [K][128] f32 weights; coalesced along nid.
        #pragma unroll
        for (int p = 0; p < 2; ++p) {
            int kk0 = (koct + 2 * p) * 8;          // {0,16} or {8,24}
            s16x8 pw;
            #pragma unroll
            for (int i = 0; i < 8; ++i)
                pw[i] = f2b(Wsrc[(size_t)(k0 + kk0 + i) * 128 + nid]);
            *(s16x8*)&Bs[nid * 32 + BSWZ(nid, kk0)] = pw;
        }
        // A tile: gather rows + mask + f32->bf16 (register staged)
        {
            unsigned o0 = rowoff[arow] + k0 + ak;
            unsigned o1 = rowoff[arow + 16] + k0 + ak;
            float m0 = rowval[arow], m1 = rowval[arow + 16];
            float4 a0 = *(const float4*)&Asrc[o0];
            float4 a1 = *(const float4*)&Asrc[o0 + 4];
            float4 b0 = *(const float4*)&Asrc[o1];
            float4 b1 = *(const float4*)&Asrc[o1 + 4];
            s16x8 pa, pb;
            pa[0]=f2b(a0.x*m0); pa[1]=f2b(a0.y*m0); pa[2]=f2b(a0.z*m0); pa[3]=f2b(a0.w*m0);
            pa[4]=f2b(a1.x*m0); pa[5]=f2b(a1.y*m0); pa[6]=f2b(a1.z*m0); pa[7]=f2b(a1.w*m0);
            pb[0]=f2b(b0.x*m1); pb[1]=f2b(b0.y*m1); pb[2]=f2b(b0.z*m1); pb[3]=f2b(b0.w*m1);
            pb[4]=f2b(b1.x*m1); pb[5]=f2b(b1.y*m1); pb[6]=f2b(b1.z*m1); pb[7]=f2b(b1.w*m1);
            *(s16x8*)&As[arow * 32 + ak]        = pa;
            *(s16x8*)&As[(arow + 16) * 32 + ak] = pb;
        }
        __syncthreads();
        s16x8 af[4], bfv[4];
        #pragma unroll
        for (int mi = 0; mi < 4; ++mi)
            af[mi] = *(const s16x8*)&As[(wr * 64 + mi * 16 + fr) * 32 + qk];
        #pragma unroll
        for (int ni = 0; ni < 4; ++ni) {
            int rr = wc * 64 + ni * 16 + fr;
            bfv[ni] = *(const s16x8*)&Bs[rr * 32 + BSWZ(rr, qk)];
        }
        #pragma unroll
        for (int mi = 0; mi < 4; ++mi)
            #pragma unroll
            for (int ni = 0; ni < 4; ++ni)
                acc[mi][ni] = __builtin_amdgcn_mfma_f32_16x16x32_bf16(
                    af[mi], bfv[ni], acc[mi][ni], 0, 0, 0);
    }
    int crow = (lane >> 4) * 4;
    #pragma unroll
    for (int mi = 0; mi < 4; ++mi) {
        #pragma unroll
        for (int ni = 0; ni < 4; ++ni) {
            int gc = col0 + wc * 64 + ni * 16 + fr;
            int gr = row0 + wr * 64 + mi * 16 + crow;
            #pragma unroll
            for (int rg = 0; rg < 4; ++rg) {
                float v = acc[mi][ni][rg];
                int r = gr + rg;
                if (route == 0) {
                    if (gc < 128) Y [(size_t)r * WN + gc]       = v;
                    else          Xp[(size_t)r * WN + gc - 128] = v;
                } else if (route == 1) {
                    G1[(size_t)r * WE + gc] = v;
                } else {
                    ci[(size_t)r * CIW + 384 + gc] = __float2bfloat16(fmaxf(v, 0.f));
                }
            }
        }
    }
}

// ---------------------------------------------------------------- K24:
// blocks 0..255:      h = relu(A @ Y) -> neh           (was k2)
// blocks 256..8447:   line GCN, scatter-add into AGG   (was k4; 2 edges/block)
__global__ __launch_bounds__(256) void k24(
    const float* __restrict__ adj, const int* __restrict__ nobj,
    const float* __restrict__ Y, float* __restrict__ neh,
    const float* __restrict__ la, const float* __restrict__ G1,
    const int* __restrict__ eidx, const int* __restrict__ nedg,
    float* __restrict__ AGG)
{
    __shared__ union {
        struct { float As[16 * 129]; } k2;
        struct { int idxs[2][MM]; float vals[2][MM]; int cnt[2]; } k4;
    } S;
    int t = threadIdx.x;

    if (blockIdx.x < 256) {                       // ---------- k2 ----------
        int vb = blockIdx.x;
        int b  = vb >> 4;
        int i0 = ((vb >> 1) & 7) * 16;
        int ch = vb & 1;
        int s  = nobj[b];
        if (t < 128) {
            for (int rr = 0; rr < 16; ++rr) {
                int i = i0 + rr;
                float v = 0.f;
                if (i < s) {
                    v = adj[(size_t)(b * NN + i) * NN + t] * ((t < s) ? 1.f : 0.f);
                    if (t == i) v += 1.f;
                }
                S.k2.As[rr * 129 + t] = v;
            }
        }
        __syncthreads();
        int c  = ch * 64 + (t & 63);
        int rb = (t >> 6) * 4;
        float acc[4] = {0.f, 0.f, 0.f, 0.f};
        for (int j = 0; j < NN; ++j) {
            float yv = Y[(b * NN + j) * WN + c];
            #pragma unroll
            for (int r = 0; r < 4; ++r) acc[r] += S.k2.As[(rb + r) * 129 + j] * yv;
        }
        #pragma unroll
        for (int r = 0; r < 4; ++r) {
            int i = i0 + rb + r;
            neh[(b * NN + i) * 128 + c] = fmaxf(acc[r], 0.f);
        }
    } else {                                      // ---------- k4 ----------
        int vb = blockIdx.x - 256;                // 0..8191
        int half = t >> 7;
        int ch   = t & 127;
        int b = vb >> 9;
        int m = (vb & 511) * 2 + half;
        int se = nedg[b];
        bool act = (m < se);
        if (ch == 0) S.k4.cnt[half] = 0;
        __syncthreads();
        if (act) {
            const float4* larow = (const float4*)(la + ((size_t)b * MM + m) * MM);
            #pragma unroll
            for (int pass = 0; pass < 2; ++pass) {
                int j4 = pass * 128 + ch;
                float4 v = larow[j4];
                int j0 = j4 * 4;
                int nl = (v.x != 0.f) + (v.y != 0.f) + (v.z != 0.f) + (v.w != 0.f);
                if (nl) {
                    int p = atomicAdd(&S.k4.cnt[half], nl);
                    if (v.x != 0.f) { S.k4.idxs[half][p] = j0;     S.k4.vals[half][p] = v.x; ++p; }
                    if (v.y != 0.f) { S.k4.idxs[half][p] = j0 + 1; S.k4.vals[half][p] = v.y; ++p; }
                    if (v.z != 0.f) { S.k4.idxs[half][p] = j0 + 2; S.k4.vals[half][p] = v.z; ++p; }
                    if (v.w != 0.f) { S.k4.idxs[half][p] = j0 + 3; S.k4.vals[half][p] = v.w; }
                }
            }
        }
        __syncthreads();
        if (act) {
            int n = S.k4.cnt[half];
            const float* g1b = G1 + (size_t)b * MM * WE;
            float acc = g1b[m * WE + ch];
            for (int p = 0; p < n; ++p)
                acc += S.k4.vals[half][p] * g1b[S.k4.idxs[half][p] * WE + ch];
            float gv = fmaxf(acc, 0.f);
            int src = eidx[b * 2 * MM + m];
            atomicAdd(&AGG[((size_t)b * NN + src) * 128 + ch], gv);
        }
    }
}

// ---------------------------------------------------------------- K5a:
// ci[:,0:384] (bf16) = [neh0+neh1 | agg0*m0+agg1*m1 | relu(Xp0+Xp1)]
__global__ __launch_bounds__(256) void k5a_build_ci(
    const float* __restrict__ neh, const float* __restrict__ AGG,
    const float* __restrict__ Xp,
    const int* __restrict__ opairs, const int* __restrict__ nobj,
    __hip_bfloat16* __restrict__ ci)
{
    __shared__ int   pi0[16], pi1[16];
    __shared__ float nm0[16], nm1[16];
    int b     = blockIdx.x >> 5;
    int pbase = (blockIdx.x & 31) * 16;
    int t     = threadIdx.x;
    int s     = nobj[b];
    if (t < 16) {
        int p  = pbase + t;
        int i0 = opairs[(b * PP + p) * 2];
        int i1 = opairs[(b * PP + p) * 2 + 1];
        pi0[t] = i0; pi1[t] = i1;
        nm0[t] = (i0 < s) ? 1.f : 0.f;
        nm1[t] = (i1 < s) ? 1.f : 0.f;
    }
    __syncthreads();
    for (int pp = 0; pp < 16; ++pp) {
        int i0 = pi0[pp], i1 = pi1[pp];
        int p  = pbase + pp;
        __hip_bfloat16* cirow = ci + (size_t)(b * PP + p) * CIW;
        float v;
        if (t < 128) {
            v = neh[(b * NN + i0) * 128 + t] + neh[(b * NN + i1) * 128 + t];
        } else {
            int c = t - 128;
            v = AGG[(b * NN + i0) * 128 + c] * nm0[pp]
              + AGG[(b * NN + i1) * 128 + c] * nm1[pp];
        }
        cirow[t] = __float2bfloat16(v);
        if (t < 128) {
            float pm = Xp[(b * NN + i0) * WN + t] + Xp[(b * NN + i1) * WN + t];
            cirow[256 + t] = __float2bfloat16(fmaxf(pm, 0.f));
        }
    }
}

// ---------------------------------------------------------------- K6:
// hid(bf16) = relu(ci @ W1cat + b1cat), (8192x512)@(512x768), bf16 MFMA.
// A staged via gl_lds; B staged DIRECTLY from per-head W1 [512][256] f32.
__global__ __launch_bounds__(256) void k6_mlp1_mfma(
    const ushort* __restrict__ A,   // ci  [8192][512] bf16
    const float* __restrict__ lrW1, const float* __restrict__ scrW1,
    const float* __restrict__ mrW1,
    const float* __restrict__ lrb1, const float* __restrict__ scrb1,
    const float* __restrict__ mrb1,
    __hip_bfloat16* __restrict__ H) // hid [8192][768] bf16
{
    __shared__ ushort As[128 * 32];
    __shared__ ushort Bs[128 * 32];
    int t    = threadIdx.x;
    int col0 = blockIdx.x * 128;
    int row0 = blockIdx.y * 128;
    const float* W1h = (col0 < 256) ? lrW1 : (col0 < 512) ? scrW1 : mrW1;
    const float* bh  = (col0 < 256) ? lrb1 : (col0 < 512) ? scrb1 : mrb1;
    int cih = col0 & 255;
    int lane = t & 63;
    int w    = t >> 6;
    int wr   = w >> 1, wc = w & 1;
    int qk   = (lane >> 4) * 8;
    int fr   = lane & 15;
    int sr   = t >> 2;
    int sk   = (t & 3) * 8;
    int nid  = t & 127;
    int koct = t >> 7;
    f32x4 acc[4][4];
    #pragma unroll
    for (int i = 0; i < 4; ++i)
        #pragma unroll
        for (int j = 0; j < 4; ++j) acc[i][j] = (f32x4){0.f, 0.f, 0.f, 0.f};

    for (int k0 = 0; k0 < CIW; k0 += 32) {
        __syncthreads();
        gl_lds16(&A[(size_t)(row0 + sr) * CIW + k0 + sk],      &As[t * 8]);
        gl_lds16(&A[(size_t)(row0 + sr + 64) * CIW + k0 + sk], &As[t * 8 + 2048]);
        #pragma unroll
        for (int p = 0; p < 2; ++p) {
            int kk0 = (koct + 2 * p) * 8;
            s16x8 pw;
            #pragma unroll
            for (int i = 0; i < 8; ++i)
                pw[i] = f2b(W1h[(size_t)(k0 + kk0 + i) * 256 + cih + nid]);
            *(s16x8*)&Bs[nid * 32 + BSWZ(nid, kk0)] = pw;
        }
        __syncthreads();
        s16x8 af[4], bfv[4];
        #pragma unroll
        for (int mi = 0; mi < 4; ++mi)
            af[mi] = *(const s16x8*)&As[(wr * 64 + mi * 16 + fr) * 32 + qk];
        #pragma unroll
        for (int ni = 0; ni < 4; ++ni) {
            int rr = wc * 64 + ni * 16 + fr;
            bfv[ni] = *(const s16x8*)&Bs[rr * 32 + BSWZ(rr, qk)];
        }
        #pragma unroll
        for (int mi = 0; mi < 4; ++mi)
            #pragma unroll
            for (int ni = 0; ni < 4; ++ni)
                acc[mi][ni] = __builtin_amdgcn_mfma_f32_16x16x32_bf16(
                    af[mi], bfv[ni], acc[mi][ni], 0, 0, 0);
    }
    int crow = (lane >> 4) * 4;
    #pragma unroll
    for (int mi = 0; mi < 4; ++mi) {
        #pragma unroll
        for (int ni = 0; ni < 4; ++ni) {
            int gc = col0 + wc * 64 + ni * 16 + fr;
            int gr = row0 + wr * 64 + mi * 16 + crow;
            float bias = bh[gc & 255];
            #pragma unroll
            for (int rg = 0; rg < 4; ++rg) {
                float v = fmaxf(acc[mi][ni][rg] + bias, 0.f);
                H[(size_t)(gr + rg) * 768 + gc] = __float2bfloat16(v);
            }
        }
    }
}

// ---------------------------------------------------------------- K7:
// out = hid @ W2 + b2 for all 3 heads. 32 lanes/pair (9+6+17=32 cols).
__global__ __launch_bounds__(256) void k7_mlp2(
    const __hip_bfloat16* __restrict__ H,   // [8192][768]
    const float* __restrict__ lrW2, const float* __restrict__ lrb2,
    const float* __restrict__ scrW2, const float* __restrict__ scrb2,
    const float* __restrict__ mrW2, const float* __restrict__ mrb2,
    float* __restrict__ outp)
{
    __shared__ float w2s[32 * 257];
    int t = threadIdx.x;
    for (int o = 0; o < 32; ++o) {
        float v;
        if (o < 9)       v = lrW2[t * 9 + o];
        else if (o < 15) v = scrW2[t * 6 + (o - 9)];
        else             v = mrW2[t * 17 + (o - 15)];
        w2s[o * 257 + t] = v;
    }
    __syncthreads();
    int p = blockIdx.x * 8 + (t >> 5);
    int o = t & 31;
    int seg = (o < 9) ? 0 : ((o < 15) ? 1 : 2);
    const ushort* hr = (const ushort*)H + (size_t)p * 768 + seg * 256;
    const float* wr = &w2s[o * 257];
    float acc = (o < 9) ? lrb2[o] : ((o < 15) ? scrb2[o - 9] : mrb2[o - 15]);
    for (int k = 0; k < HIDW; k += 8) {
        s16x8 u = *(const s16x8*)&hr[k];
        acc += bf2f((unsigned short)u[0]) * wr[k]
             + bf2f((unsigned short)u[1]) * wr[k + 1]
             + bf2f((unsigned short)u[2]) * wr[k + 2]
             + bf2f((unsigned short)u[3]) * wr[k + 3]
             + bf2f((unsigned short)u[4]) * wr[k + 4]
             + bf2f((unsigned short)u[5]) * wr[k + 5]
             + bf2f((unsigned short)u[6]) * wr[k + 6]
             + bf2f((unsigned short)u[7]) * wr[k + 7];
    }
    if (o < 9)       outp[(size_t)p * 9 + o] = acc;
    else if (o < 15) outp[8192 * 9 + (size_t)p * 6 + (o - 9)] = acc;
    else             outp[8192 * 15 + (size_t)p * 17 + (o - 15)] = acc;
}

// ----------------------------------------------------------------
extern "C" void kernel_launch(void* const* d_in, const int* in_sizes, int n_in,
                              void* d_out, int out_size, void* d_ws, size_t ws_size,
                              hipStream_t stream) {
    const float* nf    = (const float*)d_in[0];
    const float* ef    = (const float*)d_in[1];
    const float* adj   = (const float*)d_in[2];
    const float* la    = (const float*)d_in[3];
    const int*   eidx  = (const int*)d_in[4];
    const int*   opair = (const int*)d_in[5];
    const int*   nobj  = (const int*)d_in[6];
    const int*   nedg  = (const int*)d_in[7];
    const float* Wn    = (const float*)d_in[8];
    const float* We    = (const float*)d_in[9];
    const float* Wn2   = (const float*)d_in[10];
    const float* We2   = (const float*)d_in[11];
    const float* scrW1 = (const float*)d_in[12];
    const float* scrb1 = (const float*)d_in[13];
    const float* scrW2 = (const float*)d_in[14];
    const float* scrb2 = (const float*)d_in[15];
    const float* lrW1  = (const float*)d_in[16];
    const float* lrb1  = (const float*)d_in[17];
    const float* lrW2  = (const float*)d_in[18];
    const float* lrb2  = (const float*)d_in[19];
    const float* mrW1  = (const float*)d_in[20];
    const float* mrb1  = (const float*)d_in[21];
    const float* mrW2  = (const float*)d_in[22];
    const float* mrb2  = (const float*)d_in[23];

    float* ws = (float*)d_ws;
    float* Y    = ws;                      // 262144 f32
    float* Xp   = Y + 262144;              // 262144
    float* neh  = Xp + 262144;             // 262144 (node_emb h-half)
    float* AGG  = neh + 262144;            // 262144 (node_emb agg-half)
    float* G1   = AGG + 262144;            // 2097152
    float* base = G1 + 2097152;
    __hip_bfloat16* ci  = (__hip_bfloat16*)base;              // 8192*512 bf16
    __hip_bfloat16* hid = (__hip_bfloat16*)(base + 2097152);  // 8192*768 bf16

    fproj<<<256, 256, 0, stream>>>(nf, ef, eidx, opair, nobj, nedg,
                                   Wn, Wn2, We, We2, Y, Xp, G1, ci, AGG);
    k24  <<<8448, 256, 0, stream>>>(adj, nobj, Y, neh, la, G1, eidx, nedg, AGG);
    k5a_build_ci<<<BB * (PP / 16), 256, 0, stream>>>(neh, AGG, Xp, opair, nobj, ci);
    k6_mlp1_mfma<<<dim3(6, 64), 256, 0, stream>>>((const ushort*)ci,
                                                  lrW1, scrW1, mrW1,
                                                  lrb1, scrb1, mrb1, hid);
    k7_mlp2     <<<8192 / 8, 256, 0, stream>>>(hid, lrW2, lrb2, scrW2, scrb2,
                                               mrW2, mrb2, (float*)d_out);
}